// Round 1
// 463.454 us; speedup vs baseline: 1.0203x; 1.0203x over previous
//
#include <hip/hip_runtime.h>

typedef unsigned short u16;
typedef u16 u16x4 __attribute__((ext_vector_type(4)));
typedef __bf16 bf16x8 __attribute__((ext_vector_type(8)));
typedef float f32x4 __attribute__((ext_vector_type(4)));

#define NROW 8192
#define CAP 128
#define D_IN 512
#define D_HID 256
#define D_OUT 128

__device__ __forceinline__ float leaky_f(float x) { return x > 0.f ? x : 0.25f * x; }

__device__ __forceinline__ u16 f2bf_rne(float f) {
  unsigned u = __float_as_uint(f);
  u += 0x7fffu + ((u >> 16) & 1u);
  return (u16)(u >> 16);
}
__device__ __forceinline__ float bf2f(u16 v) { return __uint_as_float(((unsigned)v) << 16); }
__device__ __forceinline__ void split_bf16(float f, u16& hi, u16& lo) {
  hi = f2bf_rne(f);
  float fh = __uint_as_float(((unsigned)hi) << 16);
  lo = f2bf_rne(f - fh);
}

// ---------------- weight pack: one thread per (n, k-octet); coalesced 16B stores ----------------
__global__ __launch_bounds__(256) void k_packw(
    const float* __restrict__ W1, u16* __restrict__ B1,
    const float* __restrict__ W2, u16* __restrict__ B2,
    const float* __restrict__ Wg, u16* __restrict__ B3) {
  const float* W; u16* Bt; int K, Nc, idx;
  int pb = blockIdx.x;                     // 112 blocks: 64 (W1) | 32 (W2) | 16 (Wg)
  if (pb < 64)      { W = W1; Bt = B1; K = D_IN;  Nc = D_HID; idx = pb * 256 + threadIdx.x; }
  else if (pb < 96) { W = W2; Bt = B2; K = D_HID; Nc = D_HID; idx = (pb - 64) * 256 + threadIdx.x; }
  else              { W = Wg; Bt = B3; K = D_HID; Nc = D_OUT; idx = (pb - 96) * 256 + threadIdx.x; }
  int ko8 = K >> 3;
  int n = idx / ko8, k0 = (idx % ko8) << 3;
  alignas(16) u16 hh[8], ll[8];
#pragma unroll
  for (int j = 0; j < 8; ++j) {
    float f = W[(size_t)(k0 + j) * Nc + n];
    split_bf16(f, hh[j], ll[j]);
  }
  size_t ro = (size_t)n * 2 * K;
  *(uint4*)(Bt + ro + k0)     = *(const uint4*)hh;
  *(uint4*)(Bt + ro + K + k0) = *(const uint4*)ll;
}

// ---------------- merged: blocks [0,512) = GEMM1 (x @ W1), blocks [512,8704) = CSR build ----------------
__global__ __launch_bounds__(256) void k_csr_gemm1(const float* __restrict__ adj,
    int* __restrict__ cnt, int* __restrict__ cols, float* __restrict__ vals,
    const float* __restrict__ X, const u16* __restrict__ Bt, float* __restrict__ C) {
  __shared__ u16 Ah[64 * 40], Al[64 * 40];
  __shared__ u16 Bh[64 * 40], Bl[64 * 40];
  __shared__ int csrc;
  int b = blockIdx.x;
  int tid = threadIdx.x;
  if (b < 512) {  // GEMM1: 64x64 tile, in-register fp32->split-bf16 of x; K=512, N=256
    const int N = D_HID, K = D_IN;
    int bm = (b >> 2) * 64, bn = (b & 3) * 64;
    int wave = tid >> 6, lane = tid & 63, l15 = lane & 15, quad = lane >> 4;
    f32x4 acc[4] = {};
    int ar = tid >> 2, aj = (tid & 3) << 3;
    const float* Xrow = X + (size_t)(bm + ar) * K + aj;
    const u16* Brow = Bt + (size_t)(bn + ar) * (2 * K) + aj;
    for (int k0 = 0; k0 < K; k0 += 32) {
      alignas(16) u16 hh[8], ll[8];
      float xv[8];
      *(float4*)(xv)     = *(const float4*)(Xrow + k0);
      *(float4*)(xv + 4) = *(const float4*)(Xrow + k0 + 4);
#pragma unroll
      for (int e = 0; e < 8; ++e) split_bf16(xv[e], hh[e], ll[e]);
      *(uint4*)(&Ah[ar * 40 + aj]) = *(const uint4*)hh;
      *(uint4*)(&Al[ar * 40 + aj]) = *(const uint4*)ll;
      *(uint4*)(&Bh[ar * 40 + aj]) = *(const uint4*)(Brow + k0);
      *(uint4*)(&Bl[ar * 40 + aj]) = *(const uint4*)(Brow + K + k0);
      __syncthreads();
      bf16x8 afh = *(const bf16x8*)(&Ah[(wave * 16 + l15) * 40 + quad * 8]);
      bf16x8 afl = *(const bf16x8*)(&Al[(wave * 16 + l15) * 40 + quad * 8]);
#pragma unroll
      for (int c = 0; c < 4; ++c) {
        bf16x8 bfh = *(const bf16x8*)(&Bh[(c * 16 + l15) * 40 + quad * 8]);
        bf16x8 bfl = *(const bf16x8*)(&Bl[(c * 16 + l15) * 40 + quad * 8]);
        acc[c] = __builtin_amdgcn_mfma_f32_16x16x32_bf16(afh, bfh, acc[c], 0, 0, 0);
        acc[c] = __builtin_amdgcn_mfma_f32_16x16x32_bf16(afh, bfl, acc[c], 0, 0, 0);
        acc[c] = __builtin_amdgcn_mfma_f32_16x16x32_bf16(afl, bfh, acc[c], 0, 0, 0);
      }
      __syncthreads();
    }
#pragma unroll
    for (int c = 0; c < 4; ++c)
#pragma unroll
      for (int rg = 0; rg < 4; ++rg) {
        int rowi = bm + wave * 16 + quad * 4 + rg;   // C/D: col=lane&15, row=quad*4+reg
        int coli = bn + c * 16 + l15;
        C[(size_t)rowi * N + coli] = acc[c][rg];
      }
    return;
  }
  // CSR row build
  int i = b - 512;
  if (tid == 0) csrc = 0;
  __syncthreads();
  const float4* row = (const float4*)(adj + (size_t)i * NROW);
  for (int j4 = tid; j4 < NROW / 4; j4 += 256) {
    float4 v = row[j4];
    int base = j4 * 4;
    if (v.x > 0.f) { int s = atomicAdd(&csrc, 1); if (s < CAP) { cols[i*CAP+s] = base;   vals[i*CAP+s] = v.x; } }
    if (v.y > 0.f) { int s = atomicAdd(&csrc, 1); if (s < CAP) { cols[i*CAP+s] = base+1; vals[i*CAP+s] = v.y; } }
    if (v.z > 0.f) { int s = atomicAdd(&csrc, 1); if (s < CAP) { cols[i*CAP+s] = base+2; vals[i*CAP+s] = v.z; } }
    if (v.w > 0.f) { int s = atomicAdd(&csrc, 1); if (s < CAP) { cols[i*CAP+s] = base+3; vals[i*CAP+s] = v.w; } }
  }
  __syncthreads();
  if (tid == 0) cnt[i] = (csrc < CAP) ? csrc : CAP;
}

// ---------------- GEMM2: 64x64 tile, packed A; grid (N/64, M/64) ----------------
__global__ __launch_bounds__(256) void k_gemm(const u16* __restrict__ A, const u16* __restrict__ Bt,
    float* __restrict__ C, int N, int K) {
  __shared__ u16 Ah[64 * 40], Al[64 * 40];
  __shared__ u16 Bh[64 * 40], Bl[64 * 40];
  int tid = threadIdx.x;
  int bm = blockIdx.y * 64, bn = blockIdx.x * 64;
  int wave = tid >> 6, lane = tid & 63, l15 = lane & 15, quad = lane >> 4;
  f32x4 acc[4] = {};
  int ar = tid >> 2, aj = (tid & 3) << 3;
  const u16* Arow = A + (size_t)(bm + ar) * (2 * K) + aj;
  const u16* Brow = Bt + (size_t)(bn + ar) * (2 * K) + aj;
  for (int k0 = 0; k0 < K; k0 += 32) {
    *(uint4*)(&Ah[ar * 40 + aj]) = *(const uint4*)(Arow + k0);
    *(uint4*)(&Al[ar * 40 + aj]) = *(const uint4*)(Arow + K + k0);
    *(uint4*)(&Bh[ar * 40 + aj]) = *(const uint4*)(Brow + k0);
    *(uint4*)(&Bl[ar * 40 + aj]) = *(const uint4*)(Brow + K + k0);
    __syncthreads();
    bf16x8 afh = *(const bf16x8*)(&Ah[(wave * 16 + l15) * 40 + quad * 8]);
    bf16x8 afl = *(const bf16x8*)(&Al[(wave * 16 + l15) * 40 + quad * 8]);
#pragma unroll
    for (int c = 0; c < 4; ++c) {
      bf16x8 bfh = *(const bf16x8*)(&Bh[(c * 16 + l15) * 40 + quad * 8]);
      bf16x8 bfl = *(const bf16x8*)(&Bl[(c * 16 + l15) * 40 + quad * 8]);
      acc[c] = __builtin_amdgcn_mfma_f32_16x16x32_bf16(afh, bfh, acc[c], 0, 0, 0);
      acc[c] = __builtin_amdgcn_mfma_f32_16x16x32_bf16(afh, bfl, acc[c], 0, 0, 0);
      acc[c] = __builtin_amdgcn_mfma_f32_16x16x32_bf16(afl, bfh, acc[c], 0, 0, 0);
    }
    __syncthreads();
  }
#pragma unroll
  for (int c = 0; c < 4; ++c)
#pragma unroll
    for (int rg = 0; rg < 4; ++rg) {
      int rowi = bm + wave * 16 + quad * 4 + rg;
      int coli = bn + c * 16 + l15;
      C[(size_t)rowi * N + coli] = acc[c][rg];
    }
}

// ---------------- GEMM3: 32x128 tile (N==128); h out in bf16; fused s1/s2 (fp32-exact) ----------------
__global__ __launch_bounds__(256) void k_gemm3(const u16* __restrict__ A, const u16* __restrict__ Bt,
    u16* __restrict__ Hb, int K,
    const float* __restrict__ aptr, float* __restrict__ s1, float* __restrict__ s2) {
  __shared__ u16 Ah[32 * 40], Al[32 * 40];
  __shared__ u16 Bh[128 * 40], Bl[128 * 40];
  __shared__ float sp1[2][32], sp2[2][32];
  int tid = threadIdx.x;
  int bm = blockIdx.y * 32;
  int wave = tid >> 6, lane = tid & 63, l15 = lane & 15, quad = lane >> 4;
  int rhalf = wave >> 1, chalf = wave & 1;
  f32x4 acc[4] = {};
  int t7 = tid & 127;
  int ar = t7 >> 2, aj = (t7 & 3) << 3;
  int br = tid >> 1, bj = (tid & 1) << 4;
  const u16* Arow = A + (size_t)(bm + ar) * (2 * K) + aj + (tid < 128 ? 0 : K);
  u16* Adst = (tid < 128 ? Ah : Al) + ar * 40 + aj;
  const u16* Brow = Bt + (size_t)br * (2 * K) + bj;
  for (int k0 = 0; k0 < K; k0 += 32) {
    *(uint4*)Adst = *(const uint4*)(Arow + k0);
#pragma unroll
    for (int jj = 0; jj < 2; ++jj) {
      *(uint4*)(&Bh[br * 40 + bj + jj * 8]) = *(const uint4*)(Brow + k0 + jj * 8);
      *(uint4*)(&Bl[br * 40 + bj + jj * 8]) = *(const uint4*)(Brow + K + k0 + jj * 8);
    }
    __syncthreads();
    bf16x8 afh = *(const bf16x8*)(&Ah[(rhalf * 16 + l15) * 40 + quad * 8]);
    bf16x8 afl = *(const bf16x8*)(&Al[(rhalf * 16 + l15) * 40 + quad * 8]);
#pragma unroll
    for (int c = 0; c < 4; ++c) {
      bf16x8 bfh = *(const bf16x8*)(&Bh[(chalf * 64 + c * 16 + l15) * 40 + quad * 8]);
      bf16x8 bfl = *(const bf16x8*)(&Bl[(chalf * 64 + c * 16 + l15) * 40 + quad * 8]);
      acc[c] = __builtin_amdgcn_mfma_f32_16x16x32_bf16(afh, bfh, acc[c], 0, 0, 0);
      acc[c] = __builtin_amdgcn_mfma_f32_16x16x32_bf16(afh, bfl, acc[c], 0, 0, 0);
      acc[c] = __builtin_amdgcn_mfma_f32_16x16x32_bf16(afl, bfh, acc[c], 0, 0, 0);
    }
    __syncthreads();
  }
  // h write (bf16; only att@h consumes it — logits below from fp32 accs)
#pragma unroll
  for (int c = 0; c < 4; ++c)
#pragma unroll
    for (int rg = 0; rg < 4; ++rg) {
      int rowi = bm + rhalf * 16 + quad * 4 + rg;
      int coli = chalf * 64 + c * 16 + l15;
      Hb[(size_t)rowi * 128 + coli] = f2bf_rne(acc[c][rg]);
    }
  // fused s1/s2 from fp32 accumulators (exact logit path)
  float a1v[4], a2v[4];
#pragma unroll
  for (int c = 0; c < 4; ++c) {
    a1v[c] = aptr[chalf * 64 + c * 16 + l15];
    a2v[c] = aptr[128 + chalf * 64 + c * 16 + l15];
  }
#pragma unroll
  for (int rg = 0; rg < 4; ++rg) {
    float p1 = 0.f, p2 = 0.f;
#pragma unroll
    for (int c = 0; c < 4; ++c) { p1 = fmaf(acc[c][rg], a1v[c], p1); p2 = fmaf(acc[c][rg], a2v[c], p2); }
#pragma unroll
    for (int m = 1; m < 16; m <<= 1) { p1 += __shfl_xor(p1, m); p2 += __shfl_xor(p2, m); }
    if (l15 == 0) {
      int rloc = rhalf * 16 + quad * 4 + rg;
      sp1[chalf][rloc] = p1; sp2[chalf][rloc] = p2;
    }
  }
  __syncthreads();
  if (tid < 32) {
    s1[bm + tid] = sp1[0][tid] + sp1[1][tid];
    s2[bm + tid] = sp2[0][tid] + sp2[1][tid];
  }
}

// ---------------- SpMM + bias + leaky + 2K-split-pack: ONE WAVE PER ROW, 8-deep gather MLP ----------------
__global__ __launch_bounds__(256) void k_spmm_pack(const float* __restrict__ Hin,
    const float* __restrict__ bias, const int* __restrict__ cnt,
    const int* __restrict__ cols, const float* __restrict__ vals, u16* __restrict__ Ap) {
  __shared__ int sc[4][CAP];
  __shared__ float sv[4][CAP];
  int w = threadIdx.x >> 6, lane = threadIdx.x & 63;
  int i = blockIdx.x * 4 + w;
  int n = cnt[i];
  if (lane < n)      { sc[w][lane]      = cols[i * CAP + lane];      sv[w][lane]      = vals[i * CAP + lane]; }
  if (lane + 64 < n) { sc[w][lane + 64] = cols[i * CAP + lane + 64]; sv[w][lane + 64] = vals[i * CAP + lane + 64]; }
  __syncthreads();
  const float4* H4 = (const float4*)Hin;
  float4 acc = {0.f, 0.f, 0.f, 0.f};
  int k = 0;
  for (; k + 7 < n; k += 8) {   // 8 independent gathers in flight per wave
    int   c0 = sc[w][k],     c1 = sc[w][k + 1], c2 = sc[w][k + 2], c3 = sc[w][k + 3];
    int   c4 = sc[w][k + 4], c5 = sc[w][k + 5], c6 = sc[w][k + 6], c7 = sc[w][k + 7];
    float w0 = sv[w][k],     w1 = sv[w][k + 1], w2 = sv[w][k + 2], w3 = sv[w][k + 3];
    float w4 = sv[w][k + 4], w5 = sv[w][k + 5], w6 = sv[w][k + 6], w7 = sv[w][k + 7];
    float4 v0 = H4[(size_t)c0 * 64 + lane];
    float4 v1 = H4[(size_t)c1 * 64 + lane];
    float4 v2 = H4[(size_t)c2 * 64 + lane];
    float4 v3 = H4[(size_t)c3 * 64 + lane];
    float4 v4 = H4[(size_t)c4 * 64 + lane];
    float4 v5 = H4[(size_t)c5 * 64 + lane];
    float4 v6 = H4[(size_t)c6 * 64 + lane];
    float4 v7 = H4[(size_t)c7 * 64 + lane];
    acc.x = fmaf(w0, v0.x, acc.x); acc.y = fmaf(w0, v0.y, acc.y); acc.z = fmaf(w0, v0.z, acc.z); acc.w = fmaf(w0, v0.w, acc.w);
    acc.x = fmaf(w1, v1.x, acc.x); acc.y = fmaf(w1, v1.y, acc.y); acc.z = fmaf(w1, v1.z, acc.z); acc.w = fmaf(w1, v1.w, acc.w);
    acc.x = fmaf(w2, v2.x, acc.x); acc.y = fmaf(w2, v2.y, acc.y); acc.z = fmaf(w2, v2.z, acc.z); acc.w = fmaf(w2, v2.w, acc.w);
    acc.x = fmaf(w3, v3.x, acc.x); acc.y = fmaf(w3, v3.y, acc.y); acc.z = fmaf(w3, v3.z, acc.z); acc.w = fmaf(w3, v3.w, acc.w);
    acc.x = fmaf(w4, v4.x, acc.x); acc.y = fmaf(w4, v4.y, acc.y); acc.z = fmaf(w4, v4.z, acc.z); acc.w = fmaf(w4, v4.w, acc.w);
    acc.x = fmaf(w5, v5.x, acc.x); acc.y = fmaf(w5, v5.y, acc.y); acc.z = fmaf(w5, v5.z, acc.z); acc.w = fmaf(w5, v5.w, acc.w);
    acc.x = fmaf(w6, v6.x, acc.x); acc.y = fmaf(w6, v6.y, acc.y); acc.z = fmaf(w6, v6.z, acc.z); acc.w = fmaf(w6, v6.w, acc.w);
    acc.x = fmaf(w7, v7.x, acc.x); acc.y = fmaf(w7, v7.y, acc.y); acc.z = fmaf(w7, v7.z, acc.z); acc.w = fmaf(w7, v7.w, acc.w);
  }
  for (; k < n; ++k) {
    float wv = sv[w][k];
    float4 v = H4[(size_t)sc[w][k] * 64 + lane];
    acc.x = fmaf(wv, v.x, acc.x); acc.y = fmaf(wv, v.y, acc.y);
    acc.z = fmaf(wv, v.z, acc.z); acc.w = fmaf(wv, v.w, acc.w);
  }
  float4 bv = ((const float4*)bias)[lane];
  float r[4] = { leaky_f(acc.x + bv.x), leaky_f(acc.y + bv.y),
                 leaky_f(acc.z + bv.z), leaky_f(acc.w + bv.w) };
  u16x4 hi4, lo4;
#pragma unroll
  for (int e = 0; e < 4; ++e) { u16 hh, ll; split_bf16(r[e], hh, ll); hi4[e] = hh; lo4[e] = ll; }
  size_t ro = (size_t)i * 512;
  *(u16x4*)(Ap + ro + 4 * lane) = hi4;
  *(u16x4*)(Ap + ro + 256 + 4 * lane) = lo4;
}

// ---------------- attention: ONE WAVE PER ROW; shuffle softmax; 2-half x 4-deep gather MLP ----------------
__global__ __launch_bounds__(256) void k_attn(const u16* __restrict__ Hb,
    const float* __restrict__ s1, const float* __restrict__ s2,
    const int* __restrict__ cnt, const int* __restrict__ cols, float* __restrict__ out) {
  __shared__ int sc[4][CAP];
  __shared__ float sp[4][CAP];
  int w = threadIdx.x >> 6, lane = threadIdx.x & 63;
  int i = blockIdx.x * 4 + w;
  int n = cnt[i];
  float s1i = s1[i];
  float e0 = -1e30f, e1 = -1e30f;
  if (lane < n)      { int c = cols[i * CAP + lane];      sc[w][lane]      = c; e0 = leaky_f(s1i + s2[c]); }
  if (lane + 64 < n) { int c = cols[i * CAP + lane + 64]; sc[w][lane + 64] = c; e1 = leaky_f(s1i + s2[c]); }
  float m = fmaxf(e0, e1);
#pragma unroll
  for (int o = 32; o > 0; o >>= 1) m = fmaxf(m, __shfl_xor(m, o));
  float p0 = (lane < n)      ? expf(e0 - m) : 0.f;
  float p1 = (lane + 64 < n) ? expf(e1 - m) : 0.f;
  if (lane < n)      sp[w][lane]      = p0;
  if (lane + 64 < n) sp[w][lane + 64] = p1;
  float s = p0 + p1;
#pragma unroll
  for (int o = 32; o > 0; o >>= 1) s += __shfl_xor(s, o);
  float inv = (n > 0) ? 1.0f / s : 0.f;
  __syncthreads();
  int half = lane >> 5, t32 = lane & 31;
  float4 acc = {0.f, 0.f, 0.f, 0.f};
  int k = half;
  for (; k + 6 < n; k += 8) {   // per half-wave: 4 independent row-gathers in flight
    int   c0 = sc[w][k],     c1 = sc[w][k + 2], c2 = sc[w][k + 4], c3 = sc[w][k + 6];
    float w0 = sp[w][k],     w1 = sp[w][k + 2], w2 = sp[w][k + 4], w3 = sp[w][k + 6];
    u16x4 a0 = *(const u16x4*)(Hb + (size_t)c0 * 128 + 4 * t32);
    u16x4 a1 = *(const u16x4*)(Hb + (size_t)c1 * 128 + 4 * t32);
    u16x4 a2 = *(const u16x4*)(Hb + (size_t)c2 * 128 + 4 * t32);
    u16x4 a3 = *(const u16x4*)(Hb + (size_t)c3 * 128 + 4 * t32);
    acc.x = fmaf(w0, bf2f(a0[0]), acc.x); acc.y = fmaf(w0, bf2f(a0[1]), acc.y);
    acc.z = fmaf(w0, bf2f(a0[2]), acc.z); acc.w = fmaf(w0, bf2f(a0[3]), acc.w);
    acc.x = fmaf(w1, bf2f(a1[0]), acc.x); acc.y = fmaf(w1, bf2f(a1[1]), acc.y);
    acc.z = fmaf(w1, bf2f(a1[2]), acc.z); acc.w = fmaf(w1, bf2f(a1[3]), acc.w);
    acc.x = fmaf(w2, bf2f(a2[0]), acc.x); acc.y = fmaf(w2, bf2f(a2[1]), acc.y);
    acc.z = fmaf(w2, bf2f(a2[2]), acc.z); acc.w = fmaf(w2, bf2f(a2[3]), acc.w);
    acc.x = fmaf(w3, bf2f(a3[0]), acc.x); acc.y = fmaf(w3, bf2f(a3[1]), acc.y);
    acc.z = fmaf(w3, bf2f(a3[2]), acc.z); acc.w = fmaf(w3, bf2f(a3[3]), acc.w);
  }
  for (; k < n; k += 2) {
    float wv = sp[w][k];
    u16x4 a = *(const u16x4*)(Hb + (size_t)sc[w][k] * 128 + 4 * t32);
    acc.x = fmaf(wv, bf2f(a[0]), acc.x); acc.y = fmaf(wv, bf2f(a[1]), acc.y);
    acc.z = fmaf(wv, bf2f(a[2]), acc.z); acc.w = fmaf(wv, bf2f(a[3]), acc.w);
  }
  acc.x += __shfl_xor(acc.x, 32);
  acc.y += __shfl_xor(acc.y, 32);
  acc.z += __shfl_xor(acc.z, 32);
  acc.w += __shfl_xor(acc.w, 32);
  if (lane < 32) {
    float4 r;
    r.x = leaky_f(acc.x * inv);
    r.y = leaky_f(acc.y * inv);
    r.z = leaky_f(acc.z * inv);
    r.w = leaky_f(acc.w * inv);
    float4* o4 = (float4*)out;
    if (lane < 16) o4[(size_t)i * 16 + lane] = r;                               // mu
    else           o4[(size_t)NROW * 16 + (size_t)i * 16 + (lane - 16)] = r;    // logvar
  }
}

extern "C" void kernel_launch(void* const* d_in, const int* in_sizes, int n_in,
                              void* d_out, int out_size, void* d_ws, size_t ws_size,
                              hipStream_t stream) {
  const float* x   = (const float*)d_in[0];
  const float* adj = (const float*)d_in[1];
  const float* W1  = (const float*)d_in[2];
  const float* b1  = (const float*)d_in[3];
  const float* W2  = (const float*)d_in[4];
  const float* b2  = (const float*)d_in[5];
  const float* Wg  = (const float*)d_in[6];
  const float* a   = (const float*)d_in[7];
  float* out = (float*)d_out;

  char* ws = (char*)d_ws;
  int*   row_cnt  = (int*)  (ws + 0);          //  32 KB
  int*   row_cols = (int*)  (ws + 32768);      //   4 MB
  float* row_vals = (float*)(ws + 4227072);    //   4 MB
  u16*   B1t      = (u16*)  (ws + 8421376);    // 512 KB (256 x 1024)
  u16*   B2t      = (u16*)  (ws + 8945664);    // 256 KB (256 x 512)
  u16*   B3t      = (u16*)  (ws + 9207808);    // 128 KB (128 x 512)
  float* s1       = (float*)(ws + 9338880);    //  32 KB
  float* s2       = (float*)(ws + 9371648);    //  32 KB
  u16*   hbf      = (u16*)  (ws + 9404416);    //   2 MB (8192 x 128 bf16)
  float* H0T2     = (float*)(ws + 13598720);   //   8 MB (8192 x 256 fp32)
  u16*   Apack    = (u16*)  (ws + 21987328);   //   8 MB (8192 x 512), x1/x2 packed

  // 1. weight pack (coalesced-store mapping; must precede gemm1)
  k_packw<<<112, 256, 0, stream>>>(W1, B1t, W2, B2t, Wg, B3t);
  // 2. merged: GEMM1 (512 compute blocks) + CSR build (8192 HBM blocks) — overlap
  k_csr_gemm1<<<512 + NROW, 256, 0, stream>>>(adj, row_cnt, row_cols, row_vals, x, B1t, H0T2);
  // 3. x1 = leaky(adj @ H0 + b1) -> packed  (wave-per-row)
  k_spmm_pack<<<NROW / 4, 256, 0, stream>>>(H0T2, b1, row_cnt, row_cols, row_vals, Apack);
  // 4. T2 = x1 @ W2  (K=256)
  k_gemm<<<dim3(4, 128), 256, 0, stream>>>(Apack, B2t, H0T2, D_HID, D_HID);
  // 5. x2 = leaky(adj @ T2 + b2) -> packed  (wave-per-row)
  k_spmm_pack<<<NROW / 4, 256, 0, stream>>>(H0T2, b2, row_cnt, row_cols, row_vals, Apack);
  // 6. h (bf16) = x2 @ Wg + fused fp32 s1/s2
  k_gemm3<<<dim3(1, 256), 256, 0, stream>>>(Apack, B3t, hbf, D_HID, a, s1, s2);
  // 7. masked softmax attention (wave-per-row, shuffle softmax) + bf16 aggregate + output split
  k_attn<<<NROW / 4, 256, 0, stream>>>(hbf, s1, s2, row_cnt, row_cols, out);
}

// Round 2
// 442.663 us; speedup vs baseline: 1.0683x; 1.0470x over previous
//
#include <hip/hip_runtime.h>

typedef unsigned short u16;
typedef u16 u16x4 __attribute__((ext_vector_type(4)));
typedef __bf16 bf16x8 __attribute__((ext_vector_type(8)));
typedef float f32x4 __attribute__((ext_vector_type(4)));

#define NROW 8192
#define CAP 128
#define D_IN 512
#define D_HID 256
#define D_OUT 128

__device__ __forceinline__ float leaky_f(float x) { return x > 0.f ? x : 0.25f * x; }

__device__ __forceinline__ u16 f2bf_rne(float f) {
  unsigned u = __float_as_uint(f);
  u += 0x7fffu + ((u >> 16) & 1u);
  return (u16)(u >> 16);
}
__device__ __forceinline__ float bf2f(u16 v) { return __uint_as_float(((unsigned)v) << 16); }
__device__ __forceinline__ void split_bf16(float f, u16& hi, u16& lo) {
  hi = f2bf_rne(f);
  float fh = __uint_as_float(((unsigned)hi) << 16);
  lo = f2bf_rne(f - fh);
}

// ---------------- weight pack: one thread per (n, k-octet); coalesced 16B stores ----------------
__global__ __launch_bounds__(256) void k_packw(
    const float* __restrict__ W1, u16* __restrict__ B1,
    const float* __restrict__ W2, u16* __restrict__ B2,
    const float* __restrict__ Wg, u16* __restrict__ B3) {
  const float* W; u16* Bt; int K, Nc, idx;
  int pb = blockIdx.x;                     // 112 blocks: 64 (W1) | 32 (W2) | 16 (Wg)
  if (pb < 64)      { W = W1; Bt = B1; K = D_IN;  Nc = D_HID; idx = pb * 256 + threadIdx.x; }
  else if (pb < 96) { W = W2; Bt = B2; K = D_HID; Nc = D_HID; idx = (pb - 64) * 256 + threadIdx.x; }
  else              { W = Wg; Bt = B3; K = D_HID; Nc = D_OUT; idx = (pb - 96) * 256 + threadIdx.x; }
  int ko8 = K >> 3;
  int n = idx / ko8, k0 = (idx % ko8) << 3;
  alignas(16) u16 hh[8], ll[8];
#pragma unroll
  for (int j = 0; j < 8; ++j) {
    float f = W[(size_t)(k0 + j) * Nc + n];
    split_bf16(f, hh[j], ll[j]);
  }
  size_t ro = (size_t)n * 2 * K;
  *(uint4*)(Bt + ro + k0)     = *(const uint4*)hh;
  *(uint4*)(Bt + ro + K + k0) = *(const uint4*)ll;
}

// ---------------- merged: blocks [0,512) = GEMM1 (x @ W1, bf16 out), blocks [512,8704) = CSR build ----------------
__global__ __launch_bounds__(256) void k_csr_gemm1(const float* __restrict__ adj,
    int* __restrict__ cnt, int* __restrict__ cols, float* __restrict__ vals,
    const float* __restrict__ X, const u16* __restrict__ Bt, u16* __restrict__ C) {
  __shared__ u16 Ah[64 * 40], Al[64 * 40];
  __shared__ u16 Bh[64 * 40], Bl[64 * 40];
  __shared__ int csrc;
  int b = blockIdx.x;
  int tid = threadIdx.x;
  if (b < 512) {  // GEMM1: 64x64 tile, in-register fp32->split-bf16 of x; K=512, N=256
    const int N = D_HID, K = D_IN;
    int bm = (b >> 2) * 64, bn = (b & 3) * 64;
    int wave = tid >> 6, lane = tid & 63, l15 = lane & 15, quad = lane >> 4;
    f32x4 acc[4] = {};
    int ar = tid >> 2, aj = (tid & 3) << 3;
    const float* Xrow = X + (size_t)(bm + ar) * K + aj;
    const u16* Brow = Bt + (size_t)(bn + ar) * (2 * K) + aj;
    for (int k0 = 0; k0 < K; k0 += 32) {
      alignas(16) u16 hh[8], ll[8];
      float xv[8];
      *(float4*)(xv)     = *(const float4*)(Xrow + k0);
      *(float4*)(xv + 4) = *(const float4*)(Xrow + k0 + 4);
#pragma unroll
      for (int e = 0; e < 8; ++e) split_bf16(xv[e], hh[e], ll[e]);
      *(uint4*)(&Ah[ar * 40 + aj]) = *(const uint4*)hh;
      *(uint4*)(&Al[ar * 40 + aj]) = *(const uint4*)ll;
      *(uint4*)(&Bh[ar * 40 + aj]) = *(const uint4*)(Brow + k0);
      *(uint4*)(&Bl[ar * 40 + aj]) = *(const uint4*)(Brow + K + k0);
      __syncthreads();
      bf16x8 afh = *(const bf16x8*)(&Ah[(wave * 16 + l15) * 40 + quad * 8]);
      bf16x8 afl = *(const bf16x8*)(&Al[(wave * 16 + l15) * 40 + quad * 8]);
#pragma unroll
      for (int c = 0; c < 4; ++c) {
        bf16x8 bfh = *(const bf16x8*)(&Bh[(c * 16 + l15) * 40 + quad * 8]);
        bf16x8 bfl = *(const bf16x8*)(&Bl[(c * 16 + l15) * 40 + quad * 8]);
        acc[c] = __builtin_amdgcn_mfma_f32_16x16x32_bf16(afh, bfh, acc[c], 0, 0, 0);
        acc[c] = __builtin_amdgcn_mfma_f32_16x16x32_bf16(afh, bfl, acc[c], 0, 0, 0);
        acc[c] = __builtin_amdgcn_mfma_f32_16x16x32_bf16(afl, bfh, acc[c], 0, 0, 0);
      }
      __syncthreads();
    }
#pragma unroll
    for (int c = 0; c < 4; ++c)
#pragma unroll
      for (int rg = 0; rg < 4; ++rg) {
        int rowi = bm + wave * 16 + quad * 4 + rg;   // C/D: col=lane&15, row=quad*4+reg
        int coli = bn + c * 16 + l15;
        C[(size_t)rowi * N + coli] = f2bf_rne(acc[c][rg]);
      }
    return;
  }
  // CSR row build — ballot/prefix-scan, one LDS atomic per wave-iteration (order irrelevant)
  int i = b - 512;
  if (tid == 0) csrc = 0;
  __syncthreads();
  int lane = tid & 63;
  const float4* row = (const float4*)(adj + (size_t)i * NROW);
  for (int j4 = tid; j4 < NROW / 4; j4 += 256) {
    float4 v = row[j4];
    int base = j4 * 4;
    bool p0 = v.x > 0.f, p1 = v.y > 0.f, p2 = v.z > 0.f, p3 = v.w > 0.f;
    unsigned long long m0 = __ballot(p0), m1 = __ballot(p1);
    unsigned long long m2 = __ballot(p2), m3 = __ballot(p3);
    int c0 = __popcll(m0), c1 = __popcll(m1), c2 = __popcll(m2), c3 = __popcll(m3);
    int tot = c0 + c1 + c2 + c3;
    if (tot) {
      int wbase = 0;
      if (lane == 0) wbase = atomicAdd(&csrc, tot);
      wbase = __shfl(wbase, 0);
      unsigned long long lm = (1ULL << lane) - 1ULL;
      int o0 = wbase + __popcll(m0 & lm);
      int o1 = wbase + c0 + __popcll(m1 & lm);
      int o2 = wbase + c0 + c1 + __popcll(m2 & lm);
      int o3 = wbase + c0 + c1 + c2 + __popcll(m3 & lm);
      if (p0 && o0 < CAP) { cols[i*CAP+o0] = base;   vals[i*CAP+o0] = v.x; }
      if (p1 && o1 < CAP) { cols[i*CAP+o1] = base+1; vals[i*CAP+o1] = v.y; }
      if (p2 && o2 < CAP) { cols[i*CAP+o2] = base+2; vals[i*CAP+o2] = v.z; }
      if (p3 && o3 < CAP) { cols[i*CAP+o3] = base+3; vals[i*CAP+o3] = v.w; }
    }
  }
  __syncthreads();
  if (tid == 0) cnt[i] = (csrc < CAP) ? csrc : CAP;
}

// ---------------- GEMM2: 64x64 tile, packed A; bf16 out; grid (N/64, M/64) ----------------
__global__ __launch_bounds__(256) void k_gemm(const u16* __restrict__ A, const u16* __restrict__ Bt,
    u16* __restrict__ C, int N, int K) {
  __shared__ u16 Ah[64 * 40], Al[64 * 40];
  __shared__ u16 Bh[64 * 40], Bl[64 * 40];
  int tid = threadIdx.x;
  int bm = blockIdx.y * 64, bn = blockIdx.x * 64;
  int wave = tid >> 6, lane = tid & 63, l15 = lane & 15, quad = lane >> 4;
  f32x4 acc[4] = {};
  int ar = tid >> 2, aj = (tid & 3) << 3;
  const u16* Arow = A + (size_t)(bm + ar) * (2 * K) + aj;
  const u16* Brow = Bt + (size_t)(bn + ar) * (2 * K) + aj;
  for (int k0 = 0; k0 < K; k0 += 32) {
    *(uint4*)(&Ah[ar * 40 + aj]) = *(const uint4*)(Arow + k0);
    *(uint4*)(&Al[ar * 40 + aj]) = *(const uint4*)(Arow + K + k0);
    *(uint4*)(&Bh[ar * 40 + aj]) = *(const uint4*)(Brow + k0);
    *(uint4*)(&Bl[ar * 40 + aj]) = *(const uint4*)(Brow + K + k0);
    __syncthreads();
    bf16x8 afh = *(const bf16x8*)(&Ah[(wave * 16 + l15) * 40 + quad * 8]);
    bf16x8 afl = *(const bf16x8*)(&Al[(wave * 16 + l15) * 40 + quad * 8]);
#pragma unroll
    for (int c = 0; c < 4; ++c) {
      bf16x8 bfh = *(const bf16x8*)(&Bh[(c * 16 + l15) * 40 + quad * 8]);
      bf16x8 bfl = *(const bf16x8*)(&Bl[(c * 16 + l15) * 40 + quad * 8]);
      acc[c] = __builtin_amdgcn_mfma_f32_16x16x32_bf16(afh, bfh, acc[c], 0, 0, 0);
      acc[c] = __builtin_amdgcn_mfma_f32_16x16x32_bf16(afh, bfl, acc[c], 0, 0, 0);
      acc[c] = __builtin_amdgcn_mfma_f32_16x16x32_bf16(afl, bfh, acc[c], 0, 0, 0);
    }
    __syncthreads();
  }
#pragma unroll
  for (int c = 0; c < 4; ++c)
#pragma unroll
    for (int rg = 0; rg < 4; ++rg) {
      int rowi = bm + wave * 16 + quad * 4 + rg;
      int coli = bn + c * 16 + l15;
      C[(size_t)rowi * N + coli] = f2bf_rne(acc[c][rg]);
    }
}

// ---------------- GEMM3: 32x128 tile (N==128); h out in bf16; fused s1/s2 (fp32-exact) ----------------
__global__ __launch_bounds__(256) void k_gemm3(const u16* __restrict__ A, const u16* __restrict__ Bt,
    u16* __restrict__ Hb, int K,
    const float* __restrict__ aptr, float* __restrict__ s1, float* __restrict__ s2) {
  __shared__ u16 Ah[32 * 40], Al[32 * 40];
  __shared__ u16 Bh[128 * 40], Bl[128 * 40];
  __shared__ float sp1[2][32], sp2[2][32];
  int tid = threadIdx.x;
  int bm = blockIdx.y * 32;
  int wave = tid >> 6, lane = tid & 63, l15 = lane & 15, quad = lane >> 4;
  int rhalf = wave >> 1, chalf = wave & 1;
  f32x4 acc[4] = {};
  int t7 = tid & 127;
  int ar = t7 >> 2, aj = (t7 & 3) << 3;
  int br = tid >> 1, bj = (tid & 1) << 4;
  const u16* Arow = A + (size_t)(bm + ar) * (2 * K) + aj + (tid < 128 ? 0 : K);
  u16* Adst = (tid < 128 ? Ah : Al) + ar * 40 + aj;
  const u16* Brow = Bt + (size_t)br * (2 * K) + bj;
  for (int k0 = 0; k0 < K; k0 += 32) {
    *(uint4*)Adst = *(const uint4*)(Arow + k0);
#pragma unroll
    for (int jj = 0; jj < 2; ++jj) {
      *(uint4*)(&Bh[br * 40 + bj + jj * 8]) = *(const uint4*)(Brow + k0 + jj * 8);
      *(uint4*)(&Bl[br * 40 + bj + jj * 8]) = *(const uint4*)(Brow + K + k0 + jj * 8);
    }
    __syncthreads();
    bf16x8 afh = *(const bf16x8*)(&Ah[(rhalf * 16 + l15) * 40 + quad * 8]);
    bf16x8 afl = *(const bf16x8*)(&Al[(rhalf * 16 + l15) * 40 + quad * 8]);
#pragma unroll
    for (int c = 0; c < 4; ++c) {
      bf16x8 bfh = *(const bf16x8*)(&Bh[(chalf * 64 + c * 16 + l15) * 40 + quad * 8]);
      bf16x8 bfl = *(const bf16x8*)(&Bl[(chalf * 64 + c * 16 + l15) * 40 + quad * 8]);
      acc[c] = __builtin_amdgcn_mfma_f32_16x16x32_bf16(afh, bfh, acc[c], 0, 0, 0);
      acc[c] = __builtin_amdgcn_mfma_f32_16x16x32_bf16(afh, bfl, acc[c], 0, 0, 0);
      acc[c] = __builtin_amdgcn_mfma_f32_16x16x32_bf16(afl, bfh, acc[c], 0, 0, 0);
    }
    __syncthreads();
  }
  // h write (bf16; only att@h consumes it — logits below from fp32 accs)
#pragma unroll
  for (int c = 0; c < 4; ++c)
#pragma unroll
    for (int rg = 0; rg < 4; ++rg) {
      int rowi = bm + rhalf * 16 + quad * 4 + rg;
      int coli = chalf * 64 + c * 16 + l15;
      Hb[(size_t)rowi * 128 + coli] = f2bf_rne(acc[c][rg]);
    }
  // fused s1/s2 from fp32 accumulators (exact logit path)
  float a1v[4], a2v[4];
#pragma unroll
  for (int c = 0; c < 4; ++c) {
    a1v[c] = aptr[chalf * 64 + c * 16 + l15];
    a2v[c] = aptr[128 + chalf * 64 + c * 16 + l15];
  }
#pragma unroll
  for (int rg = 0; rg < 4; ++rg) {
    float p1 = 0.f, p2 = 0.f;
#pragma unroll
    for (int c = 0; c < 4; ++c) { p1 = fmaf(acc[c][rg], a1v[c], p1); p2 = fmaf(acc[c][rg], a2v[c], p2); }
#pragma unroll
    for (int m = 1; m < 16; m <<= 1) { p1 += __shfl_xor(p1, m); p2 += __shfl_xor(p2, m); }
    if (l15 == 0) {
      int rloc = rhalf * 16 + quad * 4 + rg;
      sp1[chalf][rloc] = p1; sp2[chalf][rloc] = p2;
    }
  }
  __syncthreads();
  if (tid < 32) {
    s1[bm + tid] = sp1[0][tid] + sp1[1][tid];
    s2[bm + tid] = sp2[0][tid] + sp2[1][tid];
  }
}

// ---------------- SpMM + bias + leaky + 2K-split-pack: wave-per-row, bf16 gather, 8-deep MLP ----------------
__global__ __launch_bounds__(256) void k_spmm_pack(const u16* __restrict__ Hin,
    const float* __restrict__ bias, const int* __restrict__ cnt,
    const int* __restrict__ cols, const float* __restrict__ vals, u16* __restrict__ Ap) {
  __shared__ int sc[4][CAP];
  __shared__ float sv[4][CAP];
  int w = threadIdx.x >> 6, lane = threadIdx.x & 63;
  int i = blockIdx.x * 4 + w;
  int n = cnt[i];
  if (lane < n)      { sc[w][lane]      = cols[i * CAP + lane];      sv[w][lane]      = vals[i * CAP + lane]; }
  if (lane + 64 < n) { sc[w][lane + 64] = cols[i * CAP + lane + 64]; sv[w][lane + 64] = vals[i * CAP + lane + 64]; }
  __syncthreads();
  float4 acc = {0.f, 0.f, 0.f, 0.f};
  int k = 0;
  for (; k + 7 < n; k += 8) {   // 8 independent bf16 gathers in flight per wave
    int   c0 = sc[w][k],     c1 = sc[w][k + 1], c2 = sc[w][k + 2], c3 = sc[w][k + 3];
    int   c4 = sc[w][k + 4], c5 = sc[w][k + 5], c6 = sc[w][k + 6], c7 = sc[w][k + 7];
    float w0 = sv[w][k],     w1 = sv[w][k + 1], w2 = sv[w][k + 2], w3 = sv[w][k + 3];
    float w4 = sv[w][k + 4], w5 = sv[w][k + 5], w6 = sv[w][k + 6], w7 = sv[w][k + 7];
    u16x4 v0 = *(const u16x4*)(Hin + (size_t)c0 * 256 + 4 * lane);
    u16x4 v1 = *(const u16x4*)(Hin + (size_t)c1 * 256 + 4 * lane);
    u16x4 v2 = *(const u16x4*)(Hin + (size_t)c2 * 256 + 4 * lane);
    u16x4 v3 = *(const u16x4*)(Hin + (size_t)c3 * 256 + 4 * lane);
    u16x4 v4 = *(const u16x4*)(Hin + (size_t)c4 * 256 + 4 * lane);
    u16x4 v5 = *(const u16x4*)(Hin + (size_t)c5 * 256 + 4 * lane);
    u16x4 v6 = *(const u16x4*)(Hin + (size_t)c6 * 256 + 4 * lane);
    u16x4 v7 = *(const u16x4*)(Hin + (size_t)c7 * 256 + 4 * lane);
    acc.x = fmaf(w0, bf2f(v0[0]), acc.x); acc.y = fmaf(w0, bf2f(v0[1]), acc.y);
    acc.z = fmaf(w0, bf2f(v0[2]), acc.z); acc.w = fmaf(w0, bf2f(v0[3]), acc.w);
    acc.x = fmaf(w1, bf2f(v1[0]), acc.x); acc.y = fmaf(w1, bf2f(v1[1]), acc.y);
    acc.z = fmaf(w1, bf2f(v1[2]), acc.z); acc.w = fmaf(w1, bf2f(v1[3]), acc.w);
    acc.x = fmaf(w2, bf2f(v2[0]), acc.x); acc.y = fmaf(w2, bf2f(v2[1]), acc.y);
    acc.z = fmaf(w2, bf2f(v2[2]), acc.z); acc.w = fmaf(w2, bf2f(v2[3]), acc.w);
    acc.x = fmaf(w3, bf2f(v3[0]), acc.x); acc.y = fmaf(w3, bf2f(v3[1]), acc.y);
    acc.z = fmaf(w3, bf2f(v3[2]), acc.z); acc.w = fmaf(w3, bf2f(v3[3]), acc.w);
    acc.x = fmaf(w4, bf2f(v4[0]), acc.x); acc.y = fmaf(w4, bf2f(v4[1]), acc.y);
    acc.z = fmaf(w4, bf2f(v4[2]), acc.z); acc.w = fmaf(w4, bf2f(v4[3]), acc.w);
    acc.x = fmaf(w5, bf2f(v5[0]), acc.x); acc.y = fmaf(w5, bf2f(v5[1]), acc.y);
    acc.z = fmaf(w5, bf2f(v5[2]), acc.z); acc.w = fmaf(w5, bf2f(v5[3]), acc.w);
    acc.x = fmaf(w6, bf2f(v6[0]), acc.x); acc.y = fmaf(w6, bf2f(v6[1]), acc.y);
    acc.z = fmaf(w6, bf2f(v6[2]), acc.z); acc.w = fmaf(w6, bf2f(v6[3]), acc.w);
    acc.x = fmaf(w7, bf2f(v7[0]), acc.x); acc.y = fmaf(w7, bf2f(v7[1]), acc.y);
    acc.z = fmaf(w7, bf2f(v7[2]), acc.z); acc.w = fmaf(w7, bf2f(v7[3]), acc.w);
  }
  for (; k < n; ++k) {
    float wv = sv[w][k];
    u16x4 v = *(const u16x4*)(Hin + (size_t)sc[w][k] * 256 + 4 * lane);
    acc.x = fmaf(wv, bf2f(v[0]), acc.x); acc.y = fmaf(wv, bf2f(v[1]), acc.y);
    acc.z = fmaf(wv, bf2f(v[2]), acc.z); acc.w = fmaf(wv, bf2f(v[3]), acc.w);
  }
  float4 bv = ((const float4*)bias)[lane];
  float r[4] = { leaky_f(acc.x + bv.x), leaky_f(acc.y + bv.y),
                 leaky_f(acc.z + bv.z), leaky_f(acc.w + bv.w) };
  u16x4 hi4, lo4;
#pragma unroll
  for (int e = 0; e < 4; ++e) { u16 hh, ll; split_bf16(r[e], hh, ll); hi4[e] = hh; lo4[e] = ll; }
  size_t ro = (size_t)i * 512;
  *(u16x4*)(Ap + ro + 4 * lane) = hi4;
  *(u16x4*)(Ap + ro + 256 + 4 * lane) = lo4;
}

// ---------------- attention: ONE WAVE PER ROW; shuffle softmax; 2-half x 4-deep gather MLP ----------------
__global__ __launch_bounds__(256) void k_attn(const u16* __restrict__ Hb,
    const float* __restrict__ s1, const float* __restrict__ s2,
    const int* __restrict__ cnt, const int* __restrict__ cols, float* __restrict__ out) {
  __shared__ int sc[4][CAP];
  __shared__ float sp[4][CAP];
  int w = threadIdx.x >> 6, lane = threadIdx.x & 63;
  int i = blockIdx.x * 4 + w;
  int n = cnt[i];
  float s1i = s1[i];
  float e0 = -1e30f, e1 = -1e30f;
  if (lane < n)      { int c = cols[i * CAP + lane];      sc[w][lane]      = c; e0 = leaky_f(s1i + s2[c]); }
  if (lane + 64 < n) { int c = cols[i * CAP + lane + 64]; sc[w][lane + 64] = c; e1 = leaky_f(s1i + s2[c]); }
  float m = fmaxf(e0, e1);
#pragma unroll
  for (int o = 32; o > 0; o >>= 1) m = fmaxf(m, __shfl_xor(m, o));
  float p0 = (lane < n)      ? expf(e0 - m) : 0.f;
  float p1 = (lane + 64 < n) ? expf(e1 - m) : 0.f;
  if (lane < n)      sp[w][lane]      = p0;
  if (lane + 64 < n) sp[w][lane + 64] = p1;
  float s = p0 + p1;
#pragma unroll
  for (int o = 32; o > 0; o >>= 1) s += __shfl_xor(s, o);
  float inv = (n > 0) ? 1.0f / s : 0.f;
  __syncthreads();
  int half = lane >> 5, t32 = lane & 31;
  float4 acc = {0.f, 0.f, 0.f, 0.f};
  int k = half;
  for (; k + 6 < n; k += 8) {   // per half-wave: 4 independent row-gathers in flight
    int   c0 = sc[w][k],     c1 = sc[w][k + 2], c2 = sc[w][k + 4], c3 = sc[w][k + 6];
    float w0 = sp[w][k],     w1 = sp[w][k + 2], w2 = sp[w][k + 4], w3 = sp[w][k + 6];
    u16x4 a0 = *(const u16x4*)(Hb + (size_t)c0 * 128 + 4 * t32);
    u16x4 a1 = *(const u16x4*)(Hb + (size_t)c1 * 128 + 4 * t32);
    u16x4 a2 = *(const u16x4*)(Hb + (size_t)c2 * 128 + 4 * t32);
    u16x4 a3 = *(const u16x4*)(Hb + (size_t)c3 * 128 + 4 * t32);
    acc.x = fmaf(w0, bf2f(a0[0]), acc.x); acc.y = fmaf(w0, bf2f(a0[1]), acc.y);
    acc.z = fmaf(w0, bf2f(a0[2]), acc.z); acc.w = fmaf(w0, bf2f(a0[3]), acc.w);
    acc.x = fmaf(w1, bf2f(a1[0]), acc.x); acc.y = fmaf(w1, bf2f(a1[1]), acc.y);
    acc.z = fmaf(w1, bf2f(a1[2]), acc.z); acc.w = fmaf(w1, bf2f(a1[3]), acc.w);
    acc.x = fmaf(w2, bf2f(a2[0]), acc.x); acc.y = fmaf(w2, bf2f(a2[1]), acc.y);
    acc.z = fmaf(w2, bf2f(a2[2]), acc.z); acc.w = fmaf(w2, bf2f(a2[3]), acc.w);
    acc.x = fmaf(w3, bf2f(a3[0]), acc.x); acc.y = fmaf(w3, bf2f(a3[1]), acc.y);
    acc.z = fmaf(w3, bf2f(a3[2]), acc.z); acc.w = fmaf(w3, bf2f(a3[3]), acc.w);
  }
  for (; k < n; k += 2) {
    float wv = sp[w][k];
    u16x4 a = *(const u16x4*)(Hb + (size_t)sc[w][k] * 128 + 4 * t32);
    acc.x = fmaf(wv, bf2f(a[0]), acc.x); acc.y = fmaf(wv, bf2f(a[1]), acc.y);
    acc.z = fmaf(wv, bf2f(a[2]), acc.z); acc.w = fmaf(wv, bf2f(a[3]), acc.w);
  }
  acc.x += __shfl_xor(acc.x, 32);
  acc.y += __shfl_xor(acc.y, 32);
  acc.z += __shfl_xor(acc.z, 32);
  acc.w += __shfl_xor(acc.w, 32);
  if (lane < 32) {
    float4 r;
    r.x = leaky_f(acc.x * inv);
    r.y = leaky_f(acc.y * inv);
    r.z = leaky_f(acc.z * inv);
    r.w = leaky_f(acc.w * inv);
    float4* o4 = (float4*)out;
    if (lane < 16) o4[(size_t)i * 16 + lane] = r;                               // mu
    else           o4[(size_t)NROW * 16 + (size_t)i * 16 + (lane - 16)] = r;    // logvar
  }
}

extern "C" void kernel_launch(void* const* d_in, const int* in_sizes, int n_in,
                              void* d_out, int out_size, void* d_ws, size_t ws_size,
                              hipStream_t stream) {
  const float* x   = (const float*)d_in[0];
  const float* adj = (const float*)d_in[1];
  const float* W1  = (const float*)d_in[2];
  const float* b1  = (const float*)d_in[3];
  const float* W2  = (const float*)d_in[4];
  const float* b2  = (const float*)d_in[5];
  const float* Wg  = (const float*)d_in[6];
  const float* a   = (const float*)d_in[7];
  float* out = (float*)d_out;

  char* ws = (char*)d_ws;
  int*   row_cnt  = (int*)  (ws + 0);          //  32 KB
  int*   row_cols = (int*)  (ws + 32768);      //   4 MB
  float* row_vals = (float*)(ws + 4227072);    //   4 MB
  u16*   B1t      = (u16*)  (ws + 8421376);    // 512 KB (256 x 1024)
  u16*   B2t      = (u16*)  (ws + 8945664);    // 256 KB (256 x 512)
  u16*   B3t      = (u16*)  (ws + 9207808);    // 128 KB (128 x 512)
  float* s1       = (float*)(ws + 9338880);    //  32 KB
  float* s2       = (float*)(ws + 9371648);    //  32 KB
  u16*   hbf      = (u16*)  (ws + 9404416);    //   2 MB (8192 x 128 bf16)
  u16*   H0T2     = (u16*)  (ws + 13598720);   //   4 MB (8192 x 256 bf16)
  u16*   Apack    = (u16*)  (ws + 21987328);   //   8 MB (8192 x 512), x1/x2 packed

  // 1. weight pack (coalesced-store mapping; must precede gemm1)
  k_packw<<<112, 256, 0, stream>>>(W1, B1t, W2, B2t, Wg, B3t);
  // 2. merged: GEMM1 (512 compute blocks, bf16 out) + ballot-scan CSR build (8192 HBM blocks)
  k_csr_gemm1<<<512 + NROW, 256, 0, stream>>>(adj, row_cnt, row_cols, row_vals, x, B1t, H0T2);
  // 3. x1 = leaky(adj @ H0 + b1) -> packed  (wave-per-row, bf16 gather)
  k_spmm_pack<<<NROW / 4, 256, 0, stream>>>(H0T2, b1, row_cnt, row_cols, row_vals, Apack);
  // 4. T2 = x1 @ W2  (K=256, bf16 out)
  k_gemm<<<dim3(4, 128), 256, 0, stream>>>(Apack, B2t, H0T2, D_HID, D_HID);
  // 5. x2 = leaky(adj @ T2 + b2) -> packed  (wave-per-row, bf16 gather)
  k_spmm_pack<<<NROW / 4, 256, 0, stream>>>(H0T2, b2, row_cnt, row_cols, row_vals, Apack);
  // 6. h (bf16) = x2 @ Wg + fused fp32 s1/s2
  k_gemm3<<<dim3(1, 256), 256, 0, stream>>>(Apack, B3t, hbf, D_HID, a, s1, s2);
  // 7. masked softmax attention (wave-per-row, shuffle softmax) + bf16 aggregate + output split
  k_attn<<<NROW / 4, 256, 0, stream>>>(hbf, s1, s2, row_cnt, row_cols, out);
}